// Round 1
// 146.628 us; speedup vs baseline: 1.0041x; 1.0041x over previous
//
#include <hip/hip_runtime.h>

// Problem constants
#define BATCH   8
#define NNODES  16384
#define KNBR    16
#define LATENT  128
#define DOUT    32
#define NROWS   (BATCH * NNODES)          // 131072 rows

typedef __attribute__((ext_vector_type(8))) short short8;   // 8 bf16 (4 VGPRs)
typedef __attribute__((ext_vector_type(4))) float floatx4;  // MFMA acc

__device__ __forceinline__ unsigned short f2bf(float f) {   // fp32 -> bf16 RNE
    unsigned u = __float_as_uint(f);
    u += 0x7fff + ((u >> 16) & 1);
    return (unsigned short)(u >> 16);
}

__device__ __forceinline__ float dot2bf(unsigned a, unsigned b) {
    float alo = __uint_as_float(a << 16);
    float ahi = __uint_as_float(a & 0xffff0000u);
    float blo = __uint_as_float(b << 16);
    float bhi = __uint_as_float(b & 0xffff0000u);
    return alo * blo + ahi * bhi;
}

// Direct global->LDS 16B copy (no VGPR round-trip). Size must be a literal.
__device__ __forceinline__ void gload_lds16(const float* g, void* l) {
    __builtin_amdgcn_global_load_lds(
        (const __attribute__((address_space(1))) void*)g,
        (__attribute__((address_space(3))) void*)l,
        16, 0, 0);
}

// ---------------------------------------------------------------------------
// Kernel 1 (v3): bf16 MFMA projection, 128 rows/block, 4 waves (32 rows/wave).
// A staged as *fp32* via global_load_lds (16B width): 32 KB chunk, 96 KB/CU in
// flight at 3 blocks/CU -> HBM-saturating instead of latency-bound.
// LDS dest is linear (hardware: uniform base + lane*16); bank conflicts on the
// 256 B-stride fp32 rows are fixed by an XOR swizzle applied on BOTH sides:
// pre-swizzled global source address + swizzled ds_read address (rule #21).
//   phys(L) = L ^ ((row(L)&7) << 4), involution within each row.
// bf16 conversion (same RNE as before) happens at LDS-read time, pre-MFMA.
// ---------------------------------------------------------------------------
#define BPAD 136    // B row stride: 128 + 8 bf16 (272 B) -> 2-way (free) reads

__global__ __launch_bounds__(256) void proj_kernel(
    const float* __restrict__ feats,
    const float* __restrict__ kw, const float* __restrict__ kb,
    const float* __restrict__ qw, const float* __restrict__ qb,
    unsigned short* __restrict__ tkb, unsigned short* __restrict__ tqb)
{
    __shared__ __align__(16) unsigned char A_raw[128 * 256]; // 32 KB fp32 chunk
    __shared__ unsigned short B_lds[64 * BPAD];              // 17 KB
    __shared__ float bias_lds[64];

    const int tid  = threadIdx.x;
    const int lane = tid & 63;
    const int w    = tid >> 6;                     // wave 0..3
    const long long blk_row = (long long)blockIdx.x * 128;

    // Stage B = [kw ; qw] as bf16: B_lds[col*BPAD + k] = W_cat[col][k]
    {
        const float4* kw4 = (const float4*)kw;     // [32 rows][32 f4]
        const float4* qw4 = (const float4*)qw;
#pragma unroll
        for (int i = 0; i < 8; ++i) {
            const int linear = i * 256 + tid;      // 0..2047
            const int row = linear >> 5;           // 0..63
            const int c4  = linear & 31;
            const float4 v = (row < 32) ? kw4[row * 32 + c4] : qw4[(row - 32) * 32 + c4];
            unsigned lo = f2bf(v.x) | ((unsigned)f2bf(v.y) << 16);
            unsigned hi = f2bf(v.z) | ((unsigned)f2bf(v.w) << 16);
            *(uint2*)&B_lds[row * BPAD + c4 * 4] = make_uint2(lo, hi);
        }
        if (tid < 64) bias_lds[tid] = (tid < 32) ? kb[tid] : qb[tid - 32];
    }

    const int m = lane & 15;   // MFMA row (A) / col (B,C)
    const int q = lane >> 4;   // quad

    floatx4 acc[2][4];
#pragma unroll
    for (int rt = 0; rt < 2; ++rt)
#pragma unroll
        for (int ct = 0; ct < 4; ++ct) acc[rt][ct] = (floatx4){0.f, 0.f, 0.f, 0.f};

    for (int ch = 0; ch < 2; ++ch) {
        if (ch) __syncthreads();   // prev chunk fully consumed before overwrite

        // Issue A-chunk staging: 128 rows x 64 fp32 = 32 KB, 8 x 16B per thread.
        // Dest L is linear (lane*16 within wave); source address is the element
        // whose swizzled position is L: col_bytes = (L&255) ^ ((row&7)<<4).
#pragma unroll
        for (int i = 0; i < 8; ++i) {
            const int L  = i * 4096 + tid * 16;
            const int r  = L >> 8;                              // 0..127
            const int c0 = (((L & 255) ^ ((r & 7) << 4)) >> 2); // fp32 col
            gload_lds16(feats + (blk_row + r) * 128 + ch * 64 + c0, A_raw + L);
        }
        __syncthreads();   // drains vmcnt -> chunk (and on ch0: B/bias) visible

#pragma unroll
        for (int ks = 0; ks < 2; ++ks) {
            const int kg = ch * 64 + ks * 32 + q * 8;  // global k for B
            short8 bf[4];
#pragma unroll
            for (int ct = 0; ct < 4; ++ct)
                bf[ct] = *(const short8*)&B_lds[(ct * 16 + m) * BPAD + kg];
#pragma unroll
            for (int rt = 0; rt < 2; ++rt) {
                const int rloc = w * 32 + rt * 16 + m;
                const int b0   = rloc * 256 + ks * 128 + q * 32;   // logical byte
                const int p0   = b0 ^ ((rloc & 7) << 4);           // swizzled
                const float4 a0 = *(const float4*)(A_raw + p0);
                const float4 a1 = *(const float4*)(A_raw + (p0 ^ 16));
                union { short8 s; unsigned u[4]; } af;
                af.u[0] = f2bf(a0.x) | ((unsigned)f2bf(a0.y) << 16);
                af.u[1] = f2bf(a0.z) | ((unsigned)f2bf(a0.w) << 16);
                af.u[2] = f2bf(a1.x) | ((unsigned)f2bf(a1.y) << 16);
                af.u[3] = f2bf(a1.z) | ((unsigned)f2bf(a1.w) << 16);
#pragma unroll
                for (int ct = 0; ct < 4; ++ct)
                    acc[rt][ct] = __builtin_amdgcn_mfma_f32_16x16x32_bf16(af.s, bf[ct], acc[rt][ct], 0, 0, 0);
            }
        }
    }

    // Epilogue: bias + bf16 store. C/D layout: col = lane&15, row = q*4+reg.
#pragma unroll
    for (int rt = 0; rt < 2; ++rt) {
#pragma unroll
        for (int reg = 0; reg < 4; ++reg) {
            const long long row = blk_row + w * 32 + rt * 16 + q * 4 + reg;
#pragma unroll
            for (int ct = 0; ct < 4; ++ct) {
                const float val = acc[rt][ct][reg] + bias_lds[ct * 16 + m];
                if (ct < 2) tkb[row * DOUT + ct * 16 + m]       = f2bf(val);
                else        tqb[row * DOUT + (ct - 2) * 16 + m] = f2bf(val);
            }
        }
    }
}

// ---------------------------------------------------------------------------
// Kernel 2: gather + scaled dot on bf16 tables, cooperative-4.
// 4 lanes read one 64B row (4 x uint4), dot in-lane, 2-step shfl reduce.
// blockIdx%8 == batch: each batch's 2MB (tk+tq bf16) fits one XCD's L2.
// idx loads / out stores use nontemporal hints so the 25 MB of streaming
// traffic does not evict the L2-resident tables.
// ---------------------------------------------------------------------------
__global__ __launch_bounds__(256) void gather_dot_kernel(
    const unsigned short* __restrict__ tkb, const unsigned short* __restrict__ tqb,
    const int* __restrict__ idx, float* __restrict__ out)
{
    const long long NK  = (long long)NNODES * KNBR;     // 262144 per batch
    const long long BNK = NK * BATCH;                   // 2097152 total

    const int b   = blockIdx.x & 7;
    const int blk = blockIdx.x >> 3;
    const int grp = threadIdx.x >> 2;   // 0..63: output within pass
    const int j   = threadIdx.x & 3;    // uint4 column within the 64B row

    const uint4* tb_k = (const uint4*)(tkb + (long long)b * NNODES * DOUT);
    const uint4* tb_q = (const uint4*)(tqb + (long long)b * NNODES * DOUT);

#pragma unroll
    for (int p = 0; p < 4; ++p) {
        const long long local = (long long)blk * 256 + p * 64 + grp;  // < NK
        const long long o     = (long long)b * NK + local;

        const int xi = __builtin_nontemporal_load(&idx[BNK + o]);        // ch 1
        const int yi = __builtin_nontemporal_load(&idx[2 * BNK + o]);    // ch 2

        const uint4 x = tb_k[(long long)xi * 4 + j];
        const uint4 y = tb_q[(long long)yi * 4 + j];
        float s = dot2bf(x.x, y.x) + dot2bf(x.y, y.y)
                + dot2bf(x.z, y.z) + dot2bf(x.w, y.w);
        s += __shfl_xor(s, 1);
        s += __shfl_xor(s, 2);
        if (j == 0)
            __builtin_nontemporal_store(s * 0.17677669529663687f, &out[o]); // 32^-0.5
    }
}

// ---------------------------------------------------------------------------
extern "C" void kernel_launch(void* const* d_in, const int* in_sizes, int n_in,
                              void* d_out, int out_size, void* d_ws, size_t ws_size,
                              hipStream_t stream)
{
    const float* feats = (const float*)d_in[0];
    const float* kw    = (const float*)d_in[1];
    const float* kb    = (const float*)d_in[2];
    const float* qw    = (const float*)d_in[3];
    const float* qb    = (const float*)d_in[4];
    const int*   idx   = (const int*)d_in[5];
    float*       out   = (float*)d_out;

    // Workspace: two bf16 tables [B*N, 32] = 8 MB each
    unsigned short* tkb = (unsigned short*)d_ws;
    unsigned short* tqb = tkb + (long long)NROWS * DOUT;

    proj_kernel<<<NROWS / 128, 256, 0, stream>>>(feats, kw, kb, qw, qb, tkb, tqb);
    gather_dot_kernel<<<(int)((long long)BATCH * NNODES * KNBR / 256), 256, 0, stream>>>(
        tkb, tqb, idx, out);
}